// Round 2
// baseline (298.888 us; speedup 1.0000x reference)
//
#include <hip/hip_runtime.h>

typedef __attribute__((ext_vector_type(8))) short bf16x8;
typedef __attribute__((ext_vector_type(16))) float f32x16;

__device__ __forceinline__ unsigned short f2b(float f) {
  unsigned x = __builtin_bit_cast(unsigned, f);
  x += 0x7fffu + ((x >> 16) & 1u);   // round-to-nearest-even
  return (unsigned short)(x >> 16);
}

// ---------------------------------------------------------------------------
// Kernel 0: W [768][384] fp32 -> Wt [384][768] bf16 (k-contiguous B-frags)
//           Y [128][384] fp32 -> Ybf bf16 + y2[l] fp32
// ---------------------------------------------------------------------------
__global__ __launch_bounds__(256) void k_prep(const float* __restrict__ W,
                                              const float* __restrict__ Y,
                                              unsigned short* __restrict__ Wt,
                                              unsigned short* __restrict__ Ybf,
                                              float* __restrict__ y2) {
  __shared__ unsigned short sT[64][72];
  int b = blockIdx.x;
  if (b < 72) {
    int bk = (b % 12) * 64, bn = (b / 12) * 64;
    int c = threadIdx.x & 63, rr = threadIdx.x >> 6;
#pragma unroll
    for (int i = 0; i < 16; i++) {
      int row = rr * 16 + i;
      sT[row][c] = f2b(W[(size_t)(bk + row) * 384 + bn + c]);
    }
    __syncthreads();
#pragma unroll
    for (int i = 0; i < 16; i++) {
      int row = rr * 16 + i;
      Wt[(size_t)(bn + row) * 768 + bk + c] = sT[c][row];
    }
  } else {
    int t = threadIdx.x;
    for (int i = t; i < 12288; i += 256) {
      float4 v = ((const float4*)Y)[i];
      ushort4 o;
      o.x = f2b(v.x); o.y = f2b(v.y); o.z = f2b(v.z); o.w = f2b(v.w);
      ((ushort4*)Ybf)[i] = o;
    }
    if (t < 128) {
      const float4* row = (const float4*)(Y + (size_t)t * 384);
      float s = 0.f;
#pragma unroll
      for (int j = 0; j < 96; j++) {
        float4 v = row[j];
        s += v.x * v.x + v.y * v.y + v.z * v.z + v.w * v.w;
      }
      y2[t] = s;
    }
  }
}

// ---------------------------------------------------------------------------
// Fused kernel, round 2: 64-row blocks, grid 512, 2 blocks/CU.
//   GEMM1: block 64x384, 8 waves, wave tile 32x96 (1x3 of 32x32x16 bf16),
//          K-step 64, 1-deep register prefetch (rA + rW) over raw barriers.
//   GEMM2: 64x128 out, wave tile 32x32, sX (bf16 x) aliases GEMM1 staging,
//          sY 1-deep register prefetch over 6 k-chunks of 64.
//   All LDS tiles: unpadded 64-short rows with XOR swizzle (slot ^= row&7)
//   on BOTH write and read sides (reg-staged, so this is legal).
//   LDS total 75 KB -> 2 blocks/CU; per-wave regs ~110 -> no spill at 128 cap.
// ---------------------------------------------------------------------------
#define SWZ(row, slot) ((((row) << 3) + ((slot) ^ ((row) & 7))) << 3)

__global__ __launch_bounds__(512, 4) void k_main(const float* __restrict__ cls,
                                                 const unsigned short* __restrict__ Wt,
                                                 const float* __restrict__ bias,
                                                 const unsigned short* __restrict__ Ybf,
                                                 const float* __restrict__ y2,
                                                 float* __restrict__ xout,
                                                 float* __restrict__ out) {
  // region0 [0, 28672): sA [64][64] swz (4096) + sW [384][64] swz (24576)
  //                     later aliased by sX [64][384] swz (24576)
  // region1 [28672, 36864): sY [128][64] swz (8192)
  __shared__ __align__(16) unsigned short sm[36864];  // 73728 B
  __shared__ float rs[64][4];
  __shared__ float sF[64];
  __shared__ float sQ[64];

  unsigned short* sA = sm;
  unsigned short* sW = sm + 4096;
  unsigned short* sX = sm;
  unsigned short* sY = sm + 28672;

  const int tid = threadIdx.x;
  const int bm = blockIdx.x * 64;
  const int wave = tid >> 6, lane = tid & 63;
  const int r = lane & 31, h = lane >> 5;
  const int rg = wave & 1, cg = wave >> 1;  // GEMM1: rows rg*32, cols cg*96

  f32x16 acc[3];
#pragma unroll
  for (int j = 0; j < 3; j++)
#pragma unroll
    for (int e = 0; e < 16; e++) acc[j][e] = 0.f;

  // staging coords: each thread owns one 8-short chunk of sA, six of sW
  const int arow = tid >> 3, akc = tid & 7;

  // ---- GEMM1: 1-deep register prefetch over raw barriers ----
  float4 rA0, rA1;
  uint4 rW[6];
  {
    const float* src = cls + (size_t)(bm + arow) * 768 + akc * 8;
    rA0 = *(const float4*)(src);
    rA1 = *(const float4*)(src + 4);
  }
#pragma unroll
  for (int it = 0; it < 6; it++) {
    int c = tid + it * 512, row = c >> 3, kc = c & 7;
    rW[it] = *(const uint4*)(Wt + (size_t)row * 768 + kc * 8);
  }

  for (int t = 0; t < 12; t++) {
    // barrier A: all waves done reading LDS tile t-1 (never drains vmcnt)
    asm volatile("s_waitcnt lgkmcnt(0)" ::: "memory");
    __builtin_amdgcn_s_barrier();

    {  // write tile t (compiler inserts counted vmcnt waits on rA/rW)
      uint4 p;
      p.x = (unsigned)f2b(rA0.x) | ((unsigned)f2b(rA0.y) << 16);
      p.y = (unsigned)f2b(rA0.z) | ((unsigned)f2b(rA0.w) << 16);
      p.z = (unsigned)f2b(rA1.x) | ((unsigned)f2b(rA1.y) << 16);
      p.w = (unsigned)f2b(rA1.z) | ((unsigned)f2b(rA1.w) << 16);
      *(uint4*)(sA + SWZ(arow, akc)) = p;
    }
#pragma unroll
    for (int it = 0; it < 6; it++) {
      int c = tid + it * 512, row = c >> 3, kc = c & 7;
      *(uint4*)(sW + SWZ(row, kc)) = rW[it];
    }

    if (t < 11) {  // issue tile t+1; stays in flight through barrier B + MFMA
      const int k0 = (t + 1) * 64;
      const float* src = cls + (size_t)(bm + arow) * 768 + k0 + akc * 8;
      rA0 = *(const float4*)(src);
      rA1 = *(const float4*)(src + 4);
#pragma unroll
      for (int it = 0; it < 6; it++) {
        int c = tid + it * 512, row = c >> 3, kc = c & 7;
        rW[it] = *(const uint4*)(Wt + (size_t)row * 768 + k0 + kc * 8);
      }
    }

    // barrier B: tile t visible
    asm volatile("s_waitcnt lgkmcnt(0)" ::: "memory");
    __builtin_amdgcn_s_barrier();

#pragma unroll
    for (int sub = 0; sub < 4; sub++) {
      const int slot = sub * 2 + h;
      bf16x8 a  = *(const bf16x8*)(sA + SWZ(rg * 32 + r, slot));
      bf16x8 b0 = *(const bf16x8*)(sW + SWZ(cg * 96 + r, slot));
      bf16x8 b1 = *(const bf16x8*)(sW + SWZ(cg * 96 + 32 + r, slot));
      bf16x8 b2 = *(const bf16x8*)(sW + SWZ(cg * 96 + 64 + r, slot));
      acc[0] = __builtin_amdgcn_mfma_f32_32x32x16_bf16(a, b0, acc[0], 0, 0, 0);
      acc[1] = __builtin_amdgcn_mfma_f32_32x32x16_bf16(a, b1, acc[1], 0, 0, 0);
      acc[2] = __builtin_amdgcn_mfma_f32_32x32x16_bf16(a, b2, acc[2], 0, 0, 0);
    }
  }

  // issue GEMM2's first sY chunk now — overlaps the expmap0 epilogue
  uint4 rY[2];
#pragma unroll
  for (int it = 0; it < 2; it++) {
    int idx = tid + it * 512, row = idx >> 3, kc = idx & 7;
    rY[it] = *(const uint4*)(Ybf + (size_t)row * 384 + kc * 8);
  }

  // ---- expmap0 epilogue: bias add + per-row ||.||^2 ----
  float bcol[3];
#pragma unroll
  for (int j = 0; j < 3; j++) bcol[j] = bias[cg * 96 + j * 32 + r];

#pragma unroll
  for (int reg = 0; reg < 16; reg++) {
    float s = 0.f;
#pragma unroll
    for (int j = 0; j < 3; j++) {
      float v = acc[j][reg] + bcol[j];
      acc[j][reg] = v;
      s += v * v;
    }
    s += __shfl_xor(s, 1);
    s += __shfl_xor(s, 2);
    s += __shfl_xor(s, 4);
    s += __shfl_xor(s, 8);
    s += __shfl_xor(s, 16);
    if (r == 0) {
      int rowl = rg * 32 + (reg & 3) + 8 * (reg >> 2) + 4 * h;
      rs[rowl][cg] = s;
    }
  }
  __syncthreads();
  if (tid < 64) {
    float n2 = rs[tid][0] + rs[tid][1] + rs[tid][2] + rs[tid][3];
    float n = fmaxf(sqrtf(n2), 1e-15f);
    float f = tanhf(n) / n;
    sF[tid] = f;
    sQ[tid] = n2 * f * f;  // ||x||^2 in fp32 (clip-sensitivity)
  }
  __syncthreads();

  // scale -> write x to global AND bf16-x into LDS (aliases dead sA/sW)
#pragma unroll
  for (int reg = 0; reg < 16; reg++) {
    int rowl = rg * 32 + (reg & 3) + 8 * (reg >> 2) + 4 * h;
    float f = sF[rowl];
#pragma unroll
    for (int j = 0; j < 3; j++) {
      float v = acc[j][reg] * f;
      int col = cg * 96 + j * 32 + r;
      xout[(size_t)(bm + rowl) * 384 + col] = v;
      int slot = col >> 3, off = col & 7;
      sX[rowl * 384 + ((slot ^ (rowl & 7)) << 3) + off] = f2b(v);
    }
  }

  // ---- GEMM2: logits = -poincare_dist(x, Y), 6 k-chunks of 64 ----
  const int rt = (wave & 1) * 32, ct = (wave >> 1) * 32;
  f32x16 acc2;
#pragma unroll
  for (int e = 0; e < 16; e++) acc2[e] = 0.f;

  for (int c = 0; c < 6; c++) {
    // c=0: sX written by all waves & sY region free; c>0: prev chunk consumed.
    // Raw barrier: x global stores stay in flight (never drained here).
    asm volatile("s_waitcnt lgkmcnt(0)" ::: "memory");
    __builtin_amdgcn_s_barrier();
#pragma unroll
    for (int it = 0; it < 2; it++) {
      int idx = tid + it * 512, row = idx >> 3, kc = idx & 7;
      *(uint4*)(sY + SWZ(row, kc)) = rY[it];
    }
    if (c < 5) {
      const int k0 = (c + 1) * 64;
#pragma unroll
      for (int it = 0; it < 2; it++) {
        int idx = tid + it * 512, row = idx >> 3, kc = idx & 7;
        rY[it] = *(const uint4*)(Ybf + (size_t)row * 384 + k0 + kc * 8);
      }
    }
    asm volatile("s_waitcnt lgkmcnt(0)" ::: "memory");
    __builtin_amdgcn_s_barrier();
#pragma unroll
    for (int sub = 0; sub < 4; sub++) {
      const int slot = sub * 2 + h;
      const int xs = c * 8 + slot;
      bf16x8 a = *(const bf16x8*)(sX + (rt + r) * 384 + ((xs ^ ((rt + r) & 7)) << 3));
      bf16x8 b = *(const bf16x8*)(sY + SWZ(ct + r, slot));
      acc2 = __builtin_amdgcn_mfma_f32_32x32x16_bf16(a, b, acc2, 0, 0, 0);
    }
  }

  const float CLIP = 0.9999800001f;  // (1 - 1e-5)^2
  float yc = y2[ct + r];
#pragma unroll
  for (int reg = 0; reg < 16; reg++) {
    int rowl = rt + (reg & 3) + 8 * (reg >> 2) + 4 * h;
    float xr = sQ[rowl];
    float xy = acc2[reg];
    float sq = xr + yc - 2.f * xy;
    float den = 1.f - 2.f * xy + xr * yc;
    float ratio = fminf(fmaxf(sq / den, 0.f), CLIP);
    float s = sqrtf(ratio);
    float dist = logf((1.f + s) / (1.f - s));  // 2*atanh(s)
    out[(size_t)(bm + rowl) * 128 + ct + r] = -dist;
  }
}

// ---------------------------------------------------------------------------
extern "C" void kernel_launch(void* const* d_in, const int* in_sizes, int n_in,
                              void* d_out, int out_size, void* d_ws, size_t ws_size,
                              hipStream_t stream) {
  const float* cls  = (const float*)d_in[0];  // [32768][768] fp32
  const float* W    = (const float*)d_in[1];  // [768][384] fp32
  const float* bias = (const float*)d_in[2];  // [384] fp32
  const float* Y    = (const float*)d_in[3];  // [128][384] fp32

  float* out_logits = (float*)d_out;                    // [32768][128] fp32
  float* out_x = out_logits + (size_t)32768 * 128;      // [32768][384] fp32

  float* x2 = (float*)d_ws;                           // (unused)
  float* y2 = x2 + 32768;                             // 128 fp32
  unsigned short* Wt = (unsigned short*)(y2 + 128);   // [384][768] bf16
  unsigned short* Ybf = Wt + (size_t)384 * 768;       // [128][384] bf16

  k_prep<<<73, 256, 0, stream>>>(W, Y, Wt, Ybf, y2);
  k_main<<<512, 512, 0, stream>>>(cls, Wt, bias, Ybf, y2, out_x, out_logits);
}

// Round 3
// 245.883 us; speedup vs baseline: 1.2156x; 1.2156x over previous
//
#include <hip/hip_runtime.h>

typedef __attribute__((ext_vector_type(8))) short bf16x8;
typedef __attribute__((ext_vector_type(16))) float f32x16;

__device__ __forceinline__ unsigned short f2b(float f) {
  unsigned x = __builtin_bit_cast(unsigned, f);
  x += 0x7fffu + ((x >> 16) & 1u);   // round-to-nearest-even
  return (unsigned short)(x >> 16);
}

// ---------------------------------------------------------------------------
// Kernel 0: W [768][384] fp32 -> Wt [384][768] bf16 (k-contiguous B-frags)
//           Y [128][384] fp32 -> Ybf bf16 + y2[l] fp32
// ---------------------------------------------------------------------------
__global__ __launch_bounds__(256) void k_prep(const float* __restrict__ W,
                                              const float* __restrict__ Y,
                                              unsigned short* __restrict__ Wt,
                                              unsigned short* __restrict__ Ybf,
                                              float* __restrict__ y2) {
  __shared__ unsigned short sT[64][72];
  int b = blockIdx.x;
  if (b < 72) {
    int bk = (b % 12) * 64, bn = (b / 12) * 64;
    int c = threadIdx.x & 63, rr = threadIdx.x >> 6;
#pragma unroll
    for (int i = 0; i < 16; i++) {
      int row = rr * 16 + i;
      sT[row][c] = f2b(W[(size_t)(bk + row) * 384 + bn + c]);
    }
    __syncthreads();
#pragma unroll
    for (int i = 0; i < 16; i++) {
      int row = rr * 16 + i;
      Wt[(size_t)(bn + row) * 768 + bk + c] = sT[c][row];
    }
  } else {
    int t = threadIdx.x;
    for (int i = t; i < 12288; i += 256) {
      float4 v = ((const float4*)Y)[i];
      ushort4 o;
      o.x = f2b(v.x); o.y = f2b(v.y); o.z = f2b(v.z); o.w = f2b(v.w);
      ((ushort4*)Ybf)[i] = o;
    }
    if (t < 128) {
      const float4* row = (const float4*)(Y + (size_t)t * 384);
      float s = 0.f;
#pragma unroll
      for (int j = 0; j < 96; j++) {
        float4 v = row[j];
        s += v.x * v.x + v.y * v.y + v.z * v.z + v.w * v.w;
      }
      y2[t] = s;
    }
  }
}

// ---------------------------------------------------------------------------
// Fused kernel, round 3: 128-row blocks, 1024 threads (16 waves), grid 256.
//   GEMM1: wave tile 32x96 (acc = 48 regs/thread), K-step 64, padded
//          conflict-free LDS (rounds 0/1: zero bank conflicts), 1-deep
//          register prefetch (1 sA chunk + 3 sW chunks per thread) over
//          RAW s_barriers (vmcnt never drained in-loop).
//   GEMM2: fused; sX (bf16 x) aliases GEMM1 staging; sY 1-deep prefetch.
//   Regs: ~60 arch + 48 acc  <= 128 cap from (1024,4) -> no spill,
//   4 waves/SIMD TLP (2x round 1).
// ---------------------------------------------------------------------------
#define LDS1 72   // GEMM1 staging row stride (64 + 8 pad)
#define LDSX 392  // sX row stride (384 + 8 pad)
#define LDSY 136  // sY row stride (128 + 8 pad)

__global__ __launch_bounds__(1024, 4) void k_main(const float* __restrict__ cls,
                                                  const unsigned short* __restrict__ Wt,
                                                  const float* __restrict__ bias,
                                                  const unsigned short* __restrict__ Ybf,
                                                  const float* __restrict__ y2,
                                                  float* __restrict__ xout,
                                                  float* __restrict__ out) {
  // region0 [0, 36864): sA [128][72] (9216) + sW [384][72] (27648) shorts
  //                     later aliased by sX [128][392] = 50176 shorts
  // region1 [50176, 67584): sY [128][136] = 17408 shorts
  __shared__ __align__(16) unsigned short sm[67584];  // 135168 B
  __shared__ float rs[128][4];
  __shared__ float sF[128];
  __shared__ float sQ[128];

  unsigned short* sA = sm;
  unsigned short* sW = sm + 9216;
  unsigned short* sX = sm;
  unsigned short* sY = sm + 50176;

  const int tid = threadIdx.x;
  const int bm = blockIdx.x * 128;
  const int wave = tid >> 6, lane = tid & 63;
  const int r = lane & 31, h = lane >> 5;
  const int rg = wave & 3, cg = wave >> 2;  // GEMM1: rows rg*32, cols cg*96

  f32x16 acc[3];
#pragma unroll
  for (int j = 0; j < 3; j++)
#pragma unroll
    for (int e = 0; e < 16; e++) acc[j][e] = 0.f;

  // staging coords: 1 sA chunk + 3 sW chunks per thread
  const int arow = tid >> 3, akc = tid & 7;  // sA: 128 rows x 8 chunks

  // ---- GEMM1: 1-deep register prefetch over raw barriers ----
  float4 rA0, rA1;
  uint4 rW[3];
  {
    const float* src = cls + (size_t)(bm + arow) * 768 + akc * 8;
    rA0 = *(const float4*)(src);
    rA1 = *(const float4*)(src + 4);
  }
#pragma unroll
  for (int it = 0; it < 3; it++) {
    int c = tid + it * 1024, row = c >> 3, kc = c & 7;
    rW[it] = *(const uint4*)(Wt + (size_t)row * 768 + kc * 8);
  }

  for (int t = 0; t < 12; t++) {
    // barrier A: all waves done reading LDS tile t-1 (never drains vmcnt)
    asm volatile("s_waitcnt lgkmcnt(0)" ::: "memory");
    __builtin_amdgcn_s_barrier();

    {  // write tile t (compiler inserts counted vmcnt waits on rA/rW)
      uint4 p;
      p.x = (unsigned)f2b(rA0.x) | ((unsigned)f2b(rA0.y) << 16);
      p.y = (unsigned)f2b(rA0.z) | ((unsigned)f2b(rA0.w) << 16);
      p.z = (unsigned)f2b(rA1.x) | ((unsigned)f2b(rA1.y) << 16);
      p.w = (unsigned)f2b(rA1.z) | ((unsigned)f2b(rA1.w) << 16);
      *(uint4*)(sA + arow * LDS1 + akc * 8) = p;
    }
#pragma unroll
    for (int it = 0; it < 3; it++) {
      int c = tid + it * 1024, row = c >> 3, kc = c & 7;
      *(uint4*)(sW + row * LDS1 + kc * 8) = rW[it];
    }

    if (t < 11) {  // issue tile t+1; stays in flight through barrier B + MFMA
      const int k0 = (t + 1) * 64;
      const float* src = cls + (size_t)(bm + arow) * 768 + k0 + akc * 8;
      rA0 = *(const float4*)(src);
      rA1 = *(const float4*)(src + 4);
#pragma unroll
      for (int it = 0; it < 3; it++) {
        int c = tid + it * 1024, row = c >> 3, kc = c & 7;
        rW[it] = *(const uint4*)(Wt + (size_t)row * 768 + k0 + kc * 8);
      }
    }

    // barrier B: tile t visible
    asm volatile("s_waitcnt lgkmcnt(0)" ::: "memory");
    __builtin_amdgcn_s_barrier();

#pragma unroll
    for (int sub = 0; sub < 4; sub++) {
      const int kk = sub * 16 + h * 8;
      bf16x8 a  = *(const bf16x8*)(sA + (rg * 32 + r) * LDS1 + kk);
      bf16x8 b0 = *(const bf16x8*)(sW + (cg * 96 + r) * LDS1 + kk);
      bf16x8 b1 = *(const bf16x8*)(sW + (cg * 96 + 32 + r) * LDS1 + kk);
      bf16x8 b2 = *(const bf16x8*)(sW + (cg * 96 + 64 + r) * LDS1 + kk);
      acc[0] = __builtin_amdgcn_mfma_f32_32x32x16_bf16(a, b0, acc[0], 0, 0, 0);
      acc[1] = __builtin_amdgcn_mfma_f32_32x32x16_bf16(a, b1, acc[1], 0, 0, 0);
      acc[2] = __builtin_amdgcn_mfma_f32_32x32x16_bf16(a, b2, acc[2], 0, 0, 0);
    }
  }

  // issue GEMM2's first sY chunk now — overlaps the expmap0 epilogue
  uint4 rY[2];
#pragma unroll
  for (int it = 0; it < 2; it++) {
    int idx = tid + it * 1024, row = idx >> 4, kc = idx & 15;
    rY[it] = *(const uint4*)(Ybf + (size_t)row * 384 + kc * 8);
  }

  // ---- expmap0 epilogue: bias add + per-row ||.||^2 ----
  float bcol[3];
#pragma unroll
  for (int j = 0; j < 3; j++) bcol[j] = bias[cg * 96 + j * 32 + r];

#pragma unroll
  for (int reg = 0; reg < 16; reg++) {
    float s = 0.f;
#pragma unroll
    for (int j = 0; j < 3; j++) {
      float v = acc[j][reg] + bcol[j];
      acc[j][reg] = v;
      s += v * v;
    }
    s += __shfl_xor(s, 1);
    s += __shfl_xor(s, 2);
    s += __shfl_xor(s, 4);
    s += __shfl_xor(s, 8);
    s += __shfl_xor(s, 16);
    if (r == 0) {
      int rowl = rg * 32 + (reg & 3) + 8 * (reg >> 2) + 4 * h;
      rs[rowl][cg] = s;
    }
  }
  // raw barrier (no vmcnt drain — x/rY traffic must stay in flight)
  asm volatile("s_waitcnt lgkmcnt(0)" ::: "memory");
  __builtin_amdgcn_s_barrier();
  if (tid < 128) {
    float n2 = rs[tid][0] + rs[tid][1] + rs[tid][2] + rs[tid][3];
    float n = fmaxf(sqrtf(n2), 1e-15f);
    float f = tanhf(n) / n;
    sF[tid] = f;
    sQ[tid] = n2 * f * f;  // ||x||^2 in fp32 (clip-sensitivity)
  }
  asm volatile("s_waitcnt lgkmcnt(0)" ::: "memory");
  __builtin_amdgcn_s_barrier();

  // scale -> write x to global AND bf16-x into LDS (aliases dead sA/sW)
#pragma unroll
  for (int reg = 0; reg < 16; reg++) {
    int rowl = rg * 32 + (reg & 3) + 8 * (reg >> 2) + 4 * h;
    float f = sF[rowl];
#pragma unroll
    for (int j = 0; j < 3; j++) {
      float v = acc[j][reg] * f;
      int col = cg * 96 + j * 32 + r;
      xout[(size_t)(bm + rowl) * 384 + col] = v;
      sX[rowl * LDSX + col] = f2b(v);
    }
  }

  // ---- GEMM2: logits = -poincare_dist(x, Y), 3 k-chunks of 128 ----
  const int rt = (wave & 3) * 32, ct = (wave >> 2) * 32;
  f32x16 acc2;
#pragma unroll
  for (int e = 0; e < 16; e++) acc2[e] = 0.f;

  for (int c = 0; c < 3; c++) {
    // c=0: sX written by all waves (sY region disjoint); c>0: prev consumed.
    // Raw barrier: x global stores stay in flight (never drained here).
    asm volatile("s_waitcnt lgkmcnt(0)" ::: "memory");
    __builtin_amdgcn_s_barrier();
#pragma unroll
    for (int it = 0; it < 2; it++) {
      int idx = tid + it * 1024, row = idx >> 4, kc = idx & 15;
      *(uint4*)(sY + row * LDSY + kc * 8) = rY[it];
    }
    if (c < 2) {
      const int k0 = (c + 1) * 128;
#pragma unroll
      for (int it = 0; it < 2; it++) {
        int idx = tid + it * 1024, row = idx >> 4, kc = idx & 15;
        rY[it] = *(const uint4*)(Ybf + (size_t)row * 384 + k0 + kc * 8);
      }
    }
    asm volatile("s_waitcnt lgkmcnt(0)" ::: "memory");
    __builtin_amdgcn_s_barrier();
#pragma unroll
    for (int sub = 0; sub < 8; sub++) {
      const int kk = sub * 16 + h * 8;
      bf16x8 a = *(const bf16x8*)(sX + (rt + r) * LDSX + c * 128 + kk);
      bf16x8 b = *(const bf16x8*)(sY + (ct + r) * LDSY + kk);
      acc2 = __builtin_amdgcn_mfma_f32_32x32x16_bf16(a, b, acc2, 0, 0, 0);
    }
  }

  const float CLIP = 0.9999800001f;  // (1 - 1e-5)^2
  float yc = y2[ct + r];
#pragma unroll
  for (int reg = 0; reg < 16; reg++) {
    int rowl = rt + (reg & 3) + 8 * (reg >> 2) + 4 * h;
    float xr = sQ[rowl];
    float xy = acc2[reg];
    float sq = xr + yc - 2.f * xy;
    float den = 1.f - 2.f * xy + xr * yc;
    float ratio = fminf(fmaxf(sq / den, 0.f), CLIP);
    float s = sqrtf(ratio);
    float dist = logf((1.f + s) / (1.f - s));  // 2*atanh(s)
    out[(size_t)(bm + rowl) * 128 + ct + r] = -dist;
  }
}

// ---------------------------------------------------------------------------
extern "C" void kernel_launch(void* const* d_in, const int* in_sizes, int n_in,
                              void* d_out, int out_size, void* d_ws, size_t ws_size,
                              hipStream_t stream) {
  const float* cls  = (const float*)d_in[0];  // [32768][768] fp32
  const float* W    = (const float*)d_in[1];  // [768][384] fp32
  const float* bias = (const float*)d_in[2];  // [384] fp32
  const float* Y    = (const float*)d_in[3];  // [128][384] fp32

  float* out_logits = (float*)d_out;                    // [32768][128] fp32
  float* out_x = out_logits + (size_t)32768 * 128;      // [32768][384] fp32

  float* x2 = (float*)d_ws;                           // (unused)
  float* y2 = x2 + 32768;                             // 128 fp32
  unsigned short* Wt = (unsigned short*)(y2 + 128);   // [384][768] bf16
  unsigned short* Ybf = Wt + (size_t)384 * 768;       // [128][384] bf16

  k_prep<<<73, 256, 0, stream>>>(W, Y, Wt, Ybf, y2);
  k_main<<<256, 1024, 0, stream>>>(cls, Wt, bias, Ybf, y2, out_x, out_logits);
}

// Round 4
// 218.878 us; speedup vs baseline: 1.3656x; 1.1234x over previous
//
#include <hip/hip_runtime.h>

typedef __attribute__((ext_vector_type(8))) short bf16x8;
typedef __attribute__((ext_vector_type(16))) float f32x16;

__device__ __forceinline__ unsigned short f2b(float f) {
  unsigned x = __builtin_bit_cast(unsigned, f);
  x += 0x7fffu + ((x >> 16) & 1u);   // round-to-nearest-even
  return (unsigned short)(x >> 16);
}

// ---------------------------------------------------------------------------
// Kernel 0: W [768][384] fp32 -> Wt [384][768] bf16 (k-contiguous B-frags)
//           Y [128][384] fp32 -> Ybf bf16 + y2[l] fp32
// ---------------------------------------------------------------------------
__global__ __launch_bounds__(256) void k_prep(const float* __restrict__ W,
                                              const float* __restrict__ Y,
                                              unsigned short* __restrict__ Wt,
                                              unsigned short* __restrict__ Ybf,
                                              float* __restrict__ y2) {
  __shared__ unsigned short sT[64][72];
  int b = blockIdx.x;
  if (b < 72) {
    int bk = (b % 12) * 64, bn = (b / 12) * 64;
    int c = threadIdx.x & 63, rr = threadIdx.x >> 6;
#pragma unroll
    for (int i = 0; i < 16; i++) {
      int row = rr * 16 + i;
      sT[row][c] = f2b(W[(size_t)(bk + row) * 384 + bn + c]);
    }
    __syncthreads();
#pragma unroll
    for (int i = 0; i < 16; i++) {
      int row = rr * 16 + i;
      Wt[(size_t)(bn + row) * 768 + bk + c] = sT[c][row];
    }
  } else {
    int t = threadIdx.x;
    for (int i = t; i < 12288; i += 256) {
      float4 v = ((const float4*)Y)[i];
      ushort4 o;
      o.x = f2b(v.x); o.y = f2b(v.y); o.z = f2b(v.z); o.w = f2b(v.w);
      ((ushort4*)Ybf)[i] = o;
    }
    if (t < 128) {
      const float4* row = (const float4*)(Y + (size_t)t * 384);
      float s = 0.f;
#pragma unroll
      for (int j = 0; j < 96; j++) {
        float4 v = row[j];
        s += v.x * v.x + v.y * v.y + v.z * v.z + v.w * v.w;
      }
      y2[t] = s;
    }
  }
}

// ---------------------------------------------------------------------------
// Fused kernel, round 4: 64-row blocks, 512 threads (8 waves), grid 512.
//   LDS 66 KB -> 2 blocks/CU: while block A waits on HBM staging, block B
//   runs MFMA (m114 co-scheduling) — attacks the block-wide barrier stall
//   that made rounds 0-3 latency-bound at ~4x the memory floor.
//   GEMM1: wave tile 32x96 (acc = 48 AGPR), K-step 64, padded LDS (zero
//          conflicts measured R0/R1/R3), cls 1-deep reg prefetch (HBM),
//          Wt loaded JIT at stage time (L2-hot, ~300cy), raw s_barriers
//          (vmcnt never drained in-loop).
//   GEMM2: fused; sX (bf16 x) aliases GEMM1 staging; B-fragments read
//          DIRECT from global Ybf (L2-resident 98 KB) — no sY, no barriers.
// ---------------------------------------------------------------------------
#define LDS1 72   // GEMM1 staging row stride (64 + 8 pad)
#define LDSX 392  // sX row stride (384 + 8 pad)

__global__ __launch_bounds__(512, 4) void k_main(const float* __restrict__ cls,
                                                 const unsigned short* __restrict__ Wt,
                                                 const float* __restrict__ bias,
                                                 const unsigned short* __restrict__ Ybf,
                                                 const float* __restrict__ y2,
                                                 float* __restrict__ xout,
                                                 float* __restrict__ out) {
  // region0: sA [64][72] (4608 sh) + sW [384][72] (27648 sh) = 32256 shorts,
  //          later aliased by sX [64][392] = 25088 shorts (fits)
  __shared__ __align__(16) unsigned short sm[32256];  // 64512 B
  __shared__ float rs[64][4];
  __shared__ float sF[64];
  __shared__ float sQ[64];

  unsigned short* sA = sm;
  unsigned short* sW = sm + 4608;
  unsigned short* sX = sm;

  const int tid = threadIdx.x;
  const int bm = blockIdx.x * 64;
  const int wave = tid >> 6, lane = tid & 63;
  const int r = lane & 31, h = lane >> 5;
  const int rg = wave & 1, cg = wave >> 1;  // GEMM1: rows rg*32, cols cg*96

  f32x16 acc[3];
#pragma unroll
  for (int j = 0; j < 3; j++)
#pragma unroll
    for (int e = 0; e < 16; e++) acc[j][e] = 0.f;

  // staging coords: 1 sA chunk per thread (64 rows x 8 chunks)
  const int arow = tid >> 3, akc = tid & 7;

  // ---- GEMM1: cls 1-deep register prefetch over raw barriers ----
  float4 rA0, rA1;
  {
    const float* src = cls + (size_t)(bm + arow) * 768 + akc * 8;
    rA0 = *(const float4*)(src);
    rA1 = *(const float4*)(src + 4);
  }

  for (int t = 0; t < 12; t++) {
    const int k0 = t * 64;
    // barrier A: all waves done reading LDS tile t-1 (never drains vmcnt)
    asm volatile("s_waitcnt lgkmcnt(0)" ::: "memory");
    __builtin_amdgcn_s_barrier();

    // Wt JIT loads (L2-hot, ~300cy) — issued first so latency overlaps sA pack
    uint4 rW[6];
#pragma unroll
    for (int it = 0; it < 6; it++) {
      int c = tid + it * 512, row = c >> 3, kc = c & 7;
      rW[it] = *(const uint4*)(Wt + (size_t)row * 768 + k0 + kc * 8);
    }

    {  // write sA tile t from prefetched cls regs
      uint4 p;
      p.x = (unsigned)f2b(rA0.x) | ((unsigned)f2b(rA0.y) << 16);
      p.y = (unsigned)f2b(rA0.z) | ((unsigned)f2b(rA0.w) << 16);
      p.z = (unsigned)f2b(rA1.x) | ((unsigned)f2b(rA1.y) << 16);
      p.w = (unsigned)f2b(rA1.z) | ((unsigned)f2b(rA1.w) << 16);
      *(uint4*)(sA + arow * LDS1 + akc * 8) = p;
    }
#pragma unroll
    for (int it = 0; it < 6; it++) {
      int c = tid + it * 512, row = c >> 3, kc = c & 7;
      *(uint4*)(sW + row * LDS1 + kc * 8) = rW[it];
    }

    if (t < 11) {  // prefetch next cls tile; in flight through barrier + MFMA
      const float* src = cls + (size_t)(bm + arow) * 768 + k0 + 64 + akc * 8;
      rA0 = *(const float4*)(src);
      rA1 = *(const float4*)(src + 4);
    }

    // barrier B: tile t visible (ds_writes drained via lgkmcnt only)
    asm volatile("s_waitcnt lgkmcnt(0)" ::: "memory");
    __builtin_amdgcn_s_barrier();

#pragma unroll
    for (int sub = 0; sub < 4; sub++) {
      const int kk = sub * 16 + h * 8;
      bf16x8 a  = *(const bf16x8*)(sA + (rg * 32 + r) * LDS1 + kk);
      bf16x8 b0 = *(const bf16x8*)(sW + (cg * 96 + r) * LDS1 + kk);
      bf16x8 b1 = *(const bf16x8*)(sW + (cg * 96 + 32 + r) * LDS1 + kk);
      bf16x8 b2 = *(const bf16x8*)(sW + (cg * 96 + 64 + r) * LDS1 + kk);
      acc[0] = __builtin_amdgcn_mfma_f32_32x32x16_bf16(a, b0, acc[0], 0, 0, 0);
      acc[1] = __builtin_amdgcn_mfma_f32_32x32x16_bf16(a, b1, acc[1], 0, 0, 0);
      acc[2] = __builtin_amdgcn_mfma_f32_32x32x16_bf16(a, b2, acc[2], 0, 0, 0);
    }
  }

  // ---- expmap0 epilogue: bias add + per-row ||.||^2 ----
  float bcol[3];
#pragma unroll
  for (int j = 0; j < 3; j++) bcol[j] = bias[cg * 96 + j * 32 + r];

#pragma unroll
  for (int reg = 0; reg < 16; reg++) {
    float s = 0.f;
#pragma unroll
    for (int j = 0; j < 3; j++) {
      float v = acc[j][reg] + bcol[j];
      acc[j][reg] = v;
      s += v * v;
    }
    s += __shfl_xor(s, 1);
    s += __shfl_xor(s, 2);
    s += __shfl_xor(s, 4);
    s += __shfl_xor(s, 8);
    s += __shfl_xor(s, 16);
    if (r == 0) {
      int rowl = rg * 32 + (reg & 3) + 8 * (reg >> 2) + 4 * h;
      rs[rowl][cg] = s;
    }
  }
  asm volatile("s_waitcnt lgkmcnt(0)" ::: "memory");
  __builtin_amdgcn_s_barrier();
  if (tid < 64) {
    float n2 = rs[tid][0] + rs[tid][1] + rs[tid][2] + rs[tid][3];
    float n = fmaxf(sqrtf(n2), 1e-15f);
    float f = tanhf(n) / n;
    sF[tid] = f;
    sQ[tid] = n2 * f * f;  // ||x||^2 in fp32 (clip-sensitivity)
  }
  asm volatile("s_waitcnt lgkmcnt(0)" ::: "memory");
  __builtin_amdgcn_s_barrier();

  // scale -> write x to global AND bf16-x into LDS (aliases dead sA/sW)
#pragma unroll
  for (int reg = 0; reg < 16; reg++) {
    int rowl = rg * 32 + (reg & 3) + 8 * (reg >> 2) + 4 * h;
    float f = sF[rowl];
#pragma unroll
    for (int j = 0; j < 3; j++) {
      float v = acc[j][reg] * f;
      int col = cg * 96 + j * 32 + r;
      xout[(size_t)(bm + rowl) * 384 + col] = v;
      sX[rowl * LDSX + col] = f2b(v);
    }
  }

  // single barrier: sX fully written; GEMM2 below is barrier-free
  asm volatile("s_waitcnt lgkmcnt(0)" ::: "memory");
  __builtin_amdgcn_s_barrier();

  // ---- GEMM2: logits = -poincare_dist(x, Y) ----
  //   out tile 64x128; wave tile 32x32; A from sX (LDS), B direct from
  //   global Ybf (L2-resident). 24 MFMA per wave, no barriers.
  const int rt = (wave & 1) * 32, ct = (wave >> 1) * 32;
  f32x16 acc2;
#pragma unroll
  for (int e = 0; e < 16; e++) acc2[e] = 0.f;

  for (int cc = 0; cc < 6; cc++) {
#pragma unroll
    for (int sub = 0; sub < 4; sub++) {
      const int kk = cc * 64 + sub * 16 + h * 8;
      bf16x8 a = *(const bf16x8*)(sX + (rt + r) * LDSX + kk);
      bf16x8 b = *(const bf16x8*)(Ybf + (size_t)(ct + r) * 384 + kk);
      acc2 = __builtin_amdgcn_mfma_f32_32x32x16_bf16(a, b, acc2, 0, 0, 0);
    }
  }

  const float CLIP = 0.9999800001f;  // (1 - 1e-5)^2
  float yc = y2[ct + r];
#pragma unroll
  for (int reg = 0; reg < 16; reg++) {
    int rowl = rt + (reg & 3) + 8 * (reg >> 2) + 4 * h;
    float xr = sQ[rowl];
    float xy = acc2[reg];
    float sq = xr + yc - 2.f * xy;
    float den = 1.f - 2.f * xy + xr * yc;
    float ratio = fminf(fmaxf(sq / den, 0.f), CLIP);
    float s = sqrtf(ratio);
    float dist = logf((1.f + s) / (1.f - s));  // 2*atanh(s)
    out[(size_t)(bm + rowl) * 128 + ct + r] = -dist;
  }
}

// ---------------------------------------------------------------------------
extern "C" void kernel_launch(void* const* d_in, const int* in_sizes, int n_in,
                              void* d_out, int out_size, void* d_ws, size_t ws_size,
                              hipStream_t stream) {
  const float* cls  = (const float*)d_in[0];  // [32768][768] fp32
  const float* W    = (const float*)d_in[1];  // [768][384] fp32
  const float* bias = (const float*)d_in[2];  // [384] fp32
  const float* Y    = (const float*)d_in[3];  // [128][384] fp32

  float* out_logits = (float*)d_out;                    // [32768][128] fp32
  float* out_x = out_logits + (size_t)32768 * 128;      // [32768][384] fp32

  float* x2 = (float*)d_ws;                           // (unused)
  float* y2 = x2 + 32768;                             // 128 fp32
  unsigned short* Wt = (unsigned short*)(y2 + 128);   // [384][768] bf16
  unsigned short* Ybf = Wt + (size_t)384 * 768;       // [128][384] bf16

  k_prep<<<73, 256, 0, stream>>>(W, Y, Wt, Ybf, y2);
  k_main<<<512, 512, 0, stream>>>(cls, Wt, bias, Ybf, y2, out_x, out_logits);
}

// Round 5
// 213.357 us; speedup vs baseline: 1.4009x; 1.0259x over previous
//
#include <hip/hip_runtime.h>

typedef __attribute__((ext_vector_type(8))) short bf16x8;
typedef __attribute__((ext_vector_type(16))) float f32x16;

__device__ __forceinline__ unsigned short f2b(float f) {
  unsigned x = __builtin_bit_cast(unsigned, f);
  x += 0x7fffu + ((x >> 16) & 1u);   // round-to-nearest-even
  return (unsigned short)(x >> 16);
}

// global -> LDS DMA, 16 B per lane, LDS dest = wave-uniform base + lane*16
__device__ __forceinline__ void dma16(const unsigned short* g, unsigned short* l) {
  __builtin_amdgcn_global_load_lds(
      (const __attribute__((address_space(1))) unsigned int*)g,
      (__attribute__((address_space(3))) unsigned int*)l, 16, 0, 0);
}

// ---------------------------------------------------------------------------
// Kernel 0: W [768][384] fp32 -> Wt fragment-major bf16:
//             frag fid = ((kt*4 + s)*2 + h)*384 + n   (kt<12, s<4, h<2, n<384)
//             frag content (8 shorts): bf16(W[kt*64 + s*16 + h*8 + i][n])
//           so one global_load_lds instruction (64 lanes x 16B) delivers 64
//           consecutive frags straight into MFMA-fragment order in LDS.
//           Y [128][384] fp32 -> Ybf bf16 + y2[l] fp32  (unchanged)
// ---------------------------------------------------------------------------
__global__ __launch_bounds__(256) void k_prep(const float* __restrict__ W,
                                              const float* __restrict__ Y,
                                              unsigned short* __restrict__ Wt,
                                              unsigned short* __restrict__ Ybf,
                                              float* __restrict__ y2) {
  int b = blockIdx.x;
  if (b < 144) {
    int fid = b * 256 + threadIdx.x;   // 36864 frags total
    int kt  = fid / 3072;
    int rem = fid - kt * 3072;
    int sh  = rem / 384;               // s*2 + h  (0..7); (s*2+h)*8 = s*16+h*8
    int n   = rem - sh * 384;
    const float* src = W + (size_t)(kt * 64 + sh * 8) * 384 + n;
    unsigned short o[8];
#pragma unroll
    for (int i = 0; i < 8; i++) o[i] = f2b(src[(size_t)i * 384]);
    uint4 p;
    p.x = (unsigned)o[0] | ((unsigned)o[1] << 16);
    p.y = (unsigned)o[2] | ((unsigned)o[3] << 16);
    p.z = (unsigned)o[4] | ((unsigned)o[5] << 16);
    p.w = (unsigned)o[6] | ((unsigned)o[7] << 16);
    *(uint4*)(Wt + (size_t)fid * 8) = p;
  } else {
    int t = threadIdx.x;
    for (int i = t; i < 12288; i += 256) {
      float4 v = ((const float4*)Y)[i];
      ushort4 o;
      o.x = f2b(v.x); o.y = f2b(v.y); o.z = f2b(v.z); o.w = f2b(v.w);
      ((ushort4*)Ybf)[i] = o;
    }
    if (t < 128) {
      const float4* row = (const float4*)(Y + (size_t)t * 384);
      float s = 0.f;
#pragma unroll
      for (int j = 0; j < 96; j++) {
        float4 v = row[j];
        s += v.x * v.x + v.y * v.y + v.z * v.z + v.w * v.w;
      }
      y2[t] = s;
    }
  }
}

// ---------------------------------------------------------------------------
// Fused kernel, round 5: 128-row blocks, 1024 threads (16 waves), grid 256.
//   GEMM1: wave tile 32x96, K-step 64, double-buffered A and W,
//          ONE raw s_barrier per K-step, counted vmcnt(2) (never 0 in-loop):
//            pack A(t) -> vmcnt(2)+lgkmcnt(0) -> barrier
//            -> DMA W(t+1) via global_load_lds (fragment-major, linear LDS)
//            -> refill cls A(t+2) regs -> MFMA(t)
//          W staging never touches VGPRs; A (the HBM stream) is 2-deep.
//   GEMM2: fused; sX (bf16 x) aliases dead GEMM1 buffers; B direct from
//          L2-resident Ybf (R4-proven).
// ---------------------------------------------------------------------------
#define LDSA 72   // padded A row stride (64 + 8): zero conflicts (R0/R1/R3/R4)
#define LDSX 392  // sX row stride (384 + 8 pad)

__global__ __launch_bounds__(1024, 4) void k_main(const float* __restrict__ cls,
                                                  const unsigned short* __restrict__ Wt,
                                                  const float* __restrict__ bias,
                                                  const unsigned short* __restrict__ Ybf,
                                                  const float* __restrict__ y2,
                                                  float* __restrict__ xout,
                                                  float* __restrict__ out) {
  // shorts: ab0 [0,9216) ab1 [9216,18432)   (A [128][72] each)
  //         wb0 [18432,43008) wb1 [43008,67584)  (W 3072 frags x 8 each)
  // sX [128][392] = 50176 shorts aliases ab0/ab1/wb0 after GEMM1.
  __shared__ __align__(16) unsigned short sm[67584];  // 135168 B
  __shared__ float rs[128][4];
  __shared__ float sF[128];
  __shared__ float sQ[128];

  const int tid = threadIdx.x;
  const int bm = blockIdx.x * 128;
  const int wave = tid >> 6, lane = tid & 63;
  const int r = lane & 31, h = lane >> 5;
  const int rg = wave & 3, cg = wave >> 2;  // GEMM1: rows rg*32, cols cg*96

  f32x16 acc[3];
#pragma unroll
  for (int j = 0; j < 3; j++)
#pragma unroll
    for (int e = 0; e < 16; e++) acc[j][e] = 0.f;

  // A staging: 1 chunk/thread (128 rows x 8 chunks of 8 floats)
  const int arow = tid >> 3, akc = tid & 7;
  const float* asrc = cls + (size_t)(bm + arow) * 768 + akc * 8;

  // ---- prologue: W(0) DMA first (oldest in vmcnt queue), then A(0), A(1) ----
  {
    unsigned short* wdst = sm + 18432;
    const unsigned short* wsrc = Wt;  // kt = 0
#pragma unroll
    for (int i = 0; i < 3; i++) {
      int fb = (wave * 3 + i) * 64;
      dma16(wsrc + (size_t)(fb + lane) * 8, wdst + fb * 8);
    }
  }
  float4 rA[2][2];
  rA[0][0] = *(const float4*)(asrc);
  rA[0][1] = *(const float4*)(asrc + 4);
  rA[1][0] = *(const float4*)(asrc + 64);
  rA[1][1] = *(const float4*)(asrc + 68);

#pragma unroll
  for (int t = 0; t < 12; t++) {
    // 1. pack A(t) into ab[t&1] (compiler inserts the counted wait for rA)
    {
      uint4 p;
      p.x = (unsigned)f2b(rA[t & 1][0].x) | ((unsigned)f2b(rA[t & 1][0].y) << 16);
      p.y = (unsigned)f2b(rA[t & 1][0].z) | ((unsigned)f2b(rA[t & 1][0].w) << 16);
      p.z = (unsigned)f2b(rA[t & 1][1].x) | ((unsigned)f2b(rA[t & 1][1].y) << 16);
      p.w = (unsigned)f2b(rA[t & 1][1].z) | ((unsigned)f2b(rA[t & 1][1].w) << 16);
      *(uint4*)(sm + (t & 1) * 9216 + arow * LDSA + akc * 8) = p;
    }
    // 2. counted wait: W(t)'s 3 DMAs done; next cls prefetch stays in flight
    if (t < 11) asm volatile("s_waitcnt vmcnt(2) lgkmcnt(0)" ::: "memory");
    else        asm volatile("s_waitcnt vmcnt(0) lgkmcnt(0)" ::: "memory");
    // 3. single barrier per K-step (raw: no implicit vmcnt drain)
    __builtin_amdgcn_s_barrier();
    // 4. DMA W(t+1) into the buffer whose readers all passed this barrier
    if (t + 1 < 12) {
      unsigned short* wdst = sm + 18432 + ((t + 1) & 1) * 24576;
      const unsigned short* wsrc = Wt + (size_t)(t + 1) * 3072 * 8;
#pragma unroll
      for (int i = 0; i < 3; i++) {
        int fb = (wave * 3 + i) * 64;
        dma16(wsrc + (size_t)(fb + lane) * 8, wdst + fb * 8);
      }
    }
    // 5. refill cls prefetch for tile t+2 (2-deep HBM pipeline)
    if (t + 2 < 12) {
      rA[t & 1][0] = *(const float4*)(asrc + (t + 2) * 64);
      rA[t & 1][1] = *(const float4*)(asrc + (t + 2) * 64 + 4);
    }
    // 6. MFMA tile t
    const unsigned short* ab = sm + (t & 1) * 9216;
    const unsigned short* wb = sm + 18432 + (t & 1) * 24576;
#pragma unroll
    for (int s = 0; s < 4; s++) {
      bf16x8 a = *(const bf16x8*)(ab + (rg * 32 + r) * LDSA + s * 16 + h * 8);
      const unsigned short* wf = wb + (size_t)((s * 2 + h) * 384) * 8;
      bf16x8 b0 = *(const bf16x8*)(wf + (size_t)(cg * 96 + r) * 8);
      bf16x8 b1 = *(const bf16x8*)(wf + (size_t)(cg * 96 + 32 + r) * 8);
      bf16x8 b2 = *(const bf16x8*)(wf + (size_t)(cg * 96 + 64 + r) * 8);
      acc[0] = __builtin_amdgcn_mfma_f32_32x32x16_bf16(a, b0, acc[0], 0, 0, 0);
      acc[1] = __builtin_amdgcn_mfma_f32_32x32x16_bf16(a, b1, acc[1], 0, 0, 0);
      acc[2] = __builtin_amdgcn_mfma_f32_32x32x16_bf16(a, b2, acc[2], 0, 0, 0);
    }
  }

  // ---- expmap0 epilogue: bias add + per-row ||.||^2 ----
  float bcol[3];
#pragma unroll
  for (int j = 0; j < 3; j++) bcol[j] = bias[cg * 96 + j * 32 + r];

#pragma unroll
  for (int reg = 0; reg < 16; reg++) {
    float s = 0.f;
#pragma unroll
    for (int j = 0; j < 3; j++) {
      float v = acc[j][reg] + bcol[j];
      acc[j][reg] = v;
      s += v * v;
    }
    s += __shfl_xor(s, 1);
    s += __shfl_xor(s, 2);
    s += __shfl_xor(s, 4);
    s += __shfl_xor(s, 8);
    s += __shfl_xor(s, 16);
    if (r == 0) {
      int rowl = rg * 32 + (reg & 3) + 8 * (reg >> 2) + 4 * h;
      rs[rowl][cg] = s;
    }
  }
  asm volatile("s_waitcnt lgkmcnt(0)" ::: "memory");
  __builtin_amdgcn_s_barrier();
  if (tid < 128) {
    float n2 = rs[tid][0] + rs[tid][1] + rs[tid][2] + rs[tid][3];
    float n = fmaxf(sqrtf(n2), 1e-15f);
    float f = tanhf(n) / n;
    sF[tid] = f;
    sQ[tid] = n2 * f * f;  // ||x||^2 in fp32 (clip-sensitivity)
  }
  asm volatile("s_waitcnt lgkmcnt(0)" ::: "memory");
  __builtin_amdgcn_s_barrier();

  // scale -> write x to global AND bf16-x into LDS (aliases dead buffers)
#pragma unroll
  for (int reg = 0; reg < 16; reg++) {
    int rowl = rg * 32 + (reg & 3) + 8 * (reg >> 2) + 4 * h;
    float f = sF[rowl];
#pragma unroll
    for (int j = 0; j < 3; j++) {
      float v = acc[j][reg] * f;
      int col = cg * 96 + j * 32 + r;
      xout[(size_t)(bm + rowl) * 384 + col] = v;
      sm[rowl * LDSX + col] = f2b(v);
    }
  }
  asm volatile("s_waitcnt lgkmcnt(0)" ::: "memory");
  __builtin_amdgcn_s_barrier();

  // ---- GEMM2: logits = -poincare_dist(x, Y); B direct from L2 Ybf ----
  const int rt = (wave & 3) * 32, ct = (wave >> 2) * 32;
  f32x16 acc2;
#pragma unroll
  for (int e = 0; e < 16; e++) acc2[e] = 0.f;

#pragma unroll
  for (int cc = 0; cc < 6; cc++) {
#pragma unroll
    for (int sub = 0; sub < 4; sub++) {
      const int kk = cc * 64 + sub * 16 + h * 8;
      bf16x8 a = *(const bf16x8*)(sm + (rt + r) * LDSX + kk);
      bf16x8 b = *(const bf16x8*)(Ybf + (size_t)(ct + r) * 384 + kk);
      acc2 = __builtin_amdgcn_mfma_f32_32x32x16_bf16(a, b, acc2, 0, 0, 0);
    }
  }

  const float CLIP = 0.9999800001f;  // (1 - 1e-5)^2
  float yc = y2[ct + r];
#pragma unroll
  for (int reg = 0; reg < 16; reg++) {
    int rowl = rt + (reg & 3) + 8 * (reg >> 2) + 4 * h;
    float xr = sQ[rowl];
    float xy = acc2[reg];
    float sq = xr + yc - 2.f * xy;
    float den = 1.f - 2.f * xy + xr * yc;
    float ratio = fminf(fmaxf(sq / den, 0.f), CLIP);
    float s = sqrtf(ratio);
    float dist = logf((1.f + s) / (1.f - s));  // 2*atanh(s)
    out[(size_t)(bm + rowl) * 128 + ct + r] = -dist;
  }
}

// ---------------------------------------------------------------------------
extern "C" void kernel_launch(void* const* d_in, const int* in_sizes, int n_in,
                              void* d_out, int out_size, void* d_ws, size_t ws_size,
                              hipStream_t stream) {
  const float* cls  = (const float*)d_in[0];  // [32768][768] fp32
  const float* W    = (const float*)d_in[1];  // [768][384] fp32
  const float* bias = (const float*)d_in[2];  // [384] fp32
  const float* Y    = (const float*)d_in[3];  // [128][384] fp32

  float* out_logits = (float*)d_out;                    // [32768][128] fp32
  float* out_x = out_logits + (size_t)32768 * 128;      // [32768][384] fp32

  float* x2 = (float*)d_ws;                           // (unused)
  float* y2 = x2 + 32768;                             // 128 fp32
  unsigned short* Wt = (unsigned short*)(y2 + 128);   // 36864 frags x 16 B
  unsigned short* Ybf = Wt + (size_t)384 * 768;       // [128][384] bf16

  k_prep<<<145, 256, 0, stream>>>(W, Y, Wt, Ybf, y2);
  k_main<<<256, 1024, 0, stream>>>(cls, Wt, bias, Ybf, y2, out_x, out_logits);
}